// Round 1
// 648.798 us; speedup vs baseline: 1.2673x; 1.2673x over previous
//
#include <hip/hip_runtime.h>
#include <stdint.h>

// ---------------------------------------------------------------------------
// StyledMLP fp32 I/O: 3x (modulated 1x1 conv + bias + leaky_relu*sqrt2).
// Internal compute: bf16 MFMA (16x16x32), fp32 accumulate.
// FULLY FUSED: 1x1 convs are column-local, so one block owns a 64-column
// n-tile and runs all 3 layers in LDS -> h0/h1 never touch HBM.
// HBM traffic: read x (256 MB) + write out (256 MB) + L2-resident W slabs.
// ---------------------------------------------------------------------------

#define B_   16
#define C_   256        // Cin = Chid = Cout
#define N_   16384
#define S_   512
#define CP   264        // padded channel dim for bf16 x-tile rows (528B)
#define NT   64         // spatial tile per block
#define SLAB_BYTES 20480            // 256 rows * 80B (32 bf16 + 8 pad)
#define SLAB_ELEMS 10240
#define XT_BYTES (NT * CP * 2)      // 33792
#define LAYER_SLAB_ELEMS (B_ * 8 * SLAB_ELEMS)
#define NSTEPS 24                   // 3 layers * 8 K-steps

typedef __attribute__((ext_vector_type(8))) short bf16x8;
typedef __attribute__((ext_vector_type(4))) float f32x4;

__device__ __forceinline__ uint16_t f2bf(float f) {
  union { float f; uint32_t u; } v; v.f = f;
  return (uint16_t)((v.u + 0x7FFFu + ((v.u >> 16) & 1u)) >> 16);
}
__device__ __forceinline__ void gl_lds16(const void* g, void* l) {
  __builtin_amdgcn_global_load_lds(
      (const __attribute__((address_space(1))) void*)g,
      (__attribute__((address_space(3))) void*)l, 16, 0, 0);
}
__device__ __forceinline__ uint16_t actbf(float v) {
  v = (v >= 0.f) ? v : 0.2f * v;
  return f2bf(v * 1.4142135623730951f);
}
__device__ __forceinline__ float actf(float v) {
  v = (v >= 0.f) ? v : 0.2f * v;
  return v * 1.4142135623730951f;
}

// ---------------------------------------------------------------------------
// Weight kernel, all 3 layers in one launch: blockIdx.x = sample,
// blockIdx.y = layer. fp32 inputs.
// style = (z @ mw^T)/sqrt(S) + mb ; wb = w*style/sqrt(Cin) ; demod ; -> bf16
// Output per (l, b, ks): 256 rows x (32 bf16 + 8 pad) = 20480B slab.
// ---------------------------------------------------------------------------
__global__ __launch_bounds__(256) void wkern(
    const float* __restrict__ z,
    const float* __restrict__ w0, const float* __restrict__ mw0,
    const float* __restrict__ mb0,
    const float* __restrict__ w1, const float* __restrict__ mw1,
    const float* __restrict__ mb1,
    const float* __restrict__ w2, const float* __restrict__ mw2,
    const float* __restrict__ mb2,
    uint16_t* __restrict__ slabs) {
  __shared__ float zsh[S_];
  __shared__ float stylesh[C_];
  const int b = blockIdx.x;
  const int l = blockIdx.y;
  const int t = threadIdx.x;
  const float* w  = (l == 0) ? w0  : (l == 1) ? w1  : w2;
  const float* mw = (l == 0) ? mw0 : (l == 1) ? mw1 : mw2;
  const float* mb = (l == 0) ? mb0 : (l == 1) ? mb1 : mb2;
  uint16_t* slab_l = slabs + (size_t)l * LAYER_SLAB_ELEMS;

  zsh[t]       = z[b * S_ + t];
  zsh[t + 256] = z[b * S_ + t + 256];
  __syncthreads();

  {  // style for input channel t
    const float* row = mw + (size_t)t * S_;
    float dot = 0.f;
    for (int j = 0; j < S_; j += 4) {
      float4 a = *(const float4*)(row + j);
      dot = fmaf(a.x, zsh[j + 0], dot);
      dot = fmaf(a.y, zsh[j + 1], dot);
      dot = fmaf(a.z, zsh[j + 2], dot);
      dot = fmaf(a.w, zsh[j + 3], dot);
    }
    stylesh[t] = dot * 0.04419417382415922f /*1/sqrt(512)*/ + mb[t];
  }
  __syncthreads();

  // output row t: modulate, demodulate, pack bf16 into K-blocked slabs
  const float* wrow = w + (size_t)t * C_;
  float ssum = 0.f;
  for (int i = 0; i < C_; i += 4) {
    float4 a = *(const float4*)(wrow + i);
    float t0 = 0.0625f * a.x * stylesh[i + 0];
    float t1 = 0.0625f * a.y * stylesh[i + 1];
    float t2 = 0.0625f * a.z * stylesh[i + 2];
    float t3 = 0.0625f * a.w * stylesh[i + 3];
    ssum = fmaf(t0, t0, fmaf(t1, t1, fmaf(t2, t2, fmaf(t3, t3, ssum))));
  }
  const float demod = rsqrtf(ssum + 1e-8f);
  for (int i = 0; i < C_; i += 8) {
    uint16_t hv[8];
#pragma unroll
    for (int k = 0; k < 8; ++k)
      hv[k] = f2bf(0.0625f * wrow[i + k] * stylesh[i + k] * demod);
    uint4 o;
    o.x = (uint32_t)hv[0] | ((uint32_t)hv[1] << 16);
    o.y = (uint32_t)hv[2] | ((uint32_t)hv[3] << 16);
    o.z = (uint32_t)hv[4] | ((uint32_t)hv[5] << 16);
    o.w = (uint32_t)hv[6] | ((uint32_t)hv[7] << 16);
    const int ks = i >> 5, off = i & 31;
    *(uint4*)(slab_l + (size_t)(b * 8 + ks) * SLAB_ELEMS + t * 40 + off) = o;
  }
}

// ---------------------------------------------------------------------------
// Fused 3-layer GEMM. One block = (sample b, 64-column n-tile).
// LDS: [0, XT)            x-tile, bf16 (n, CP) -- rewritten per layer
//      [XT, XT+20480)     W slab buf0
//      [XT+20480, +40960) W slab buf1
// Pipeline (T3 minimal 2-phase): stage next slab -> ds_read+MFMA cur ->
// s_waitcnt vmcnt(0) -> raw s_barrier. One barrier per K-step; layer
// epilogues (bias+act -> bf16 back into x-tile) get one extra barrier.
// ---------------------------------------------------------------------------
__global__ __launch_bounds__(256, 2) void fused(
    const float* __restrict__ xg, const uint16_t* __restrict__ slabs,
    const float* __restrict__ b0, const float* __restrict__ b1,
    const float* __restrict__ b2, float* __restrict__ out) {
  __shared__ __align__(16) unsigned char lds[XT_BYTES + 2 * SLAB_BYTES];
  const int bx = blockIdx.x;
  const int b = bx >> 8, tl = bx & 255;
  const int n0 = tl * NT;
  const int t = threadIdx.x;
  const int wv = t >> 6, lane = t & 63;
  const int ln = lane & 15, q = lane >> 4;

  const char* slabc = (const char*)slabs;

  // --- prologue: stage step 0 (layer 0, ks 0) into buf0 -------------------
  {
    const char* wsrc = slabc + (size_t)(b * 8) * SLAB_BYTES;
    for (int i = wv; i < 20; i += 4)
      gl_lds16(wsrc + i * 1024 + lane * 16, lds + XT_BYTES + i * 1024);
  }
  // --- x tile: (c, n) fp32 -> (n, CP) bf16 in LDS (fused transpose+cast) --
  const float* xb = xg + (size_t)b * C_ * N_ + n0;
  for (int ks = 0; ks < 8; ++ks) {
    uint16_t hv[8];
#pragma unroll
    for (int i = 0; i < 8; ++i)
      hv[i] = f2bf(xb[(size_t)(ks * 32 + wv * 8 + i) * N_ + lane]);
    uint4 o;
    o.x = (uint32_t)hv[0] | ((uint32_t)hv[1] << 16);
    o.y = (uint32_t)hv[2] | ((uint32_t)hv[3] << 16);
    o.z = (uint32_t)hv[4] | ((uint32_t)hv[5] << 16);
    o.w = (uint32_t)hv[6] | ((uint32_t)hv[7] << 16);
    *(uint4*)(lds + lane * (CP * 2) + (ks * 32 + wv * 8) * 2) = o;
  }
  __syncthreads();  // full drain once: buf0 + x-tile ready

  f32x4 acc[4][4];
#pragma unroll
  for (int mi = 0; mi < 4; ++mi)
#pragma unroll
    for (int ni = 0; ni < 4; ++ni) acc[mi][ni] = (f32x4){0.f, 0.f, 0.f, 0.f};

  for (int s = 0; s < NSTEPS; ++s) {
    const int l = s >> 3, ks = s & 7;
    const char* rbuf = (const char*)lds + XT_BYTES + (s & 1) * SLAB_BYTES;

    // stage next step's W slab into the other buffer (in flight across MFMA)
    if (s + 1 < NSTEPS) {
      const int sn = s + 1;
      const char* wsrc = slabc +
          ((size_t)(sn >> 3) * (B_ * 8) + b * 8 + (sn & 7)) * SLAB_BYTES;
      char* wdst = (char*)lds + XT_BYTES + ((s + 1) & 1) * SLAB_BYTES;
      for (int i = wv; i < 20; i += 4)
        gl_lds16(wsrc + i * 1024 + lane * 16, wdst + i * 1024);
    }

    // fragments + MFMA for current step
    bf16x8 af[4], bfr[4];
#pragma unroll
    for (int mi = 0; mi < 4; ++mi)
      af[mi] = *(const bf16x8*)(rbuf + (wv * 64 + mi * 16 + ln) * 80 + q * 16);
#pragma unroll
    for (int ni = 0; ni < 4; ++ni)
      bfr[ni] = *(const bf16x8*)((const uint16_t*)lds +
                                 (ni * 16 + ln) * CP + ks * 32 + q * 8);
#pragma unroll
    for (int mi = 0; mi < 4; ++mi)
#pragma unroll
      for (int ni = 0; ni < 4; ++ni)
        acc[mi][ni] = __builtin_amdgcn_mfma_f32_16x16x32_bf16(
            af[mi], bfr[ni], acc[mi][ni], 0, 0, 0);

    if (s + 1 < NSTEPS) {
      // next slab fully landed; all waves' reads of rbuf/xt done past here
      asm volatile("s_waitcnt vmcnt(0)" ::: "memory");
      __builtin_amdgcn_s_barrier();
      __builtin_amdgcn_sched_barrier(0);
    }

    if (ks == 7) {
      if (l < 2) {
        // layer epilogue: bias + act -> bf16, rewrite x-tile for next layer
        const float* bias = (l == 0) ? b0 : b1;
        uint16_t* ltile = (uint16_t*)lds;
#pragma unroll
        for (int mi = 0; mi < 4; ++mi) {
          const int cb = wv * 64 + mi * 16 + q * 4;
          float4 b4 = *(const float4*)(bias + cb);
#pragma unroll
          for (int ni = 0; ni < 4; ++ni) {
            const int n = ni * 16 + ln;
            uint16_t h0 = actbf(acc[mi][ni][0] + b4.x);
            uint16_t h1 = actbf(acc[mi][ni][1] + b4.y);
            uint16_t h2 = actbf(acc[mi][ni][2] + b4.z);
            uint16_t h3 = actbf(acc[mi][ni][3] + b4.w);
            uint2 pk;
            pk.x = (uint32_t)h0 | ((uint32_t)h1 << 16);
            pk.y = (uint32_t)h2 | ((uint32_t)h3 << 16);
            *(uint2*)(&ltile[n * CP + cb]) = pk;
            acc[mi][ni] = (f32x4){0.f, 0.f, 0.f, 0.f};
          }
        }
        asm volatile("s_waitcnt lgkmcnt(0)" ::: "memory");
        __builtin_amdgcn_s_barrier();
        __builtin_amdgcn_sched_barrier(0);
      } else {
        // final layer: fp32 native (b, co, n) store straight from registers
        float* obase = out + (size_t)b * C_ * N_ + n0;
#pragma unroll
        for (int mi = 0; mi < 4; ++mi) {
          const int cb = wv * 64 + mi * 16 + q * 4;
          float4 b4 = *(const float4*)(b2 + cb);
          float bb[4] = {b4.x, b4.y, b4.z, b4.w};
#pragma unroll
          for (int ni = 0; ni < 4; ++ni) {
            const int n = ni * 16 + ln;
#pragma unroll
            for (int r = 0; r < 4; ++r)
              obase[(size_t)(cb + r) * N_ + n] = actf(acc[mi][ni][r] + bb[r]);
          }
        }
      }
    }
  }
}

// ---------------------------------------------------------------------------
extern "C" void kernel_launch(void* const* d_in, const int* in_sizes, int n_in,
                              void* d_out, int out_size, void* d_ws,
                              size_t ws_size, hipStream_t stream) {
  (void)in_sizes; (void)n_in; (void)out_size; (void)ws_size;
  const float* x = (const float*)d_in[0];
  const float* z = (const float*)d_in[1];
  const float* w0  = (const float*)d_in[2];
  const float* mw0 = (const float*)d_in[3];
  const float* mb0 = (const float*)d_in[4];
  const float* bb0 = (const float*)d_in[5];
  const float* w1  = (const float*)d_in[6];
  const float* mw1 = (const float*)d_in[7];
  const float* mb1 = (const float*)d_in[8];
  const float* bb1 = (const float*)d_in[9];
  const float* w2  = (const float*)d_in[10];
  const float* mw2 = (const float*)d_in[11];
  const float* mb2 = (const float*)d_in[12];
  const float* bb2 = (const float*)d_in[13];

  uint16_t* wslabs = (uint16_t*)d_ws;  // 7.86 MB (3 layers)

  wkern<<<dim3(B_, 3), 256, 0, stream>>>(z, w0, mw0, mb0, w1, mw1, mb1,
                                         w2, mw2, mb2, wslabs);
  fused<<<B_ * 256, 256, 0, stream>>>(x, wslabs, bb0, bb1, bb2,
                                      (float*)d_out);
}

// Round 2
// 627.631 us; speedup vs baseline: 1.3101x; 1.0337x over previous
//
#include <hip/hip_runtime.h>
#include <stdint.h>

// ---------------------------------------------------------------------------
// StyledMLP fp32 I/O: 3x (modulated 1x1 conv + bias + leaky_relu*sqrt2).
// Internal compute: bf16 MFMA (16x16x32), fp32 accumulate.
// FULLY FUSED: 1x1 convs are column-local; one block owns a 64-column n-tile
// and runs all 3 layers in LDS. h0/h1 never touch HBM.
// R2: bank-conflict fix (T2). x-tile CP=256 + XOR swizzle ((n&7)<<4) on
// col-byte, applied at write/read/epilogue. W slab relaid as
// [rg32][q4][r8][16B] so ds_read slot = row&7 (conflict-free); slab shrinks
// 20480->16384 B (no pad), LDS 74.75->65.5 KB.
// ---------------------------------------------------------------------------

#define B_   16
#define C_   256        // Cin = Chid = Cout
#define N_   16384
#define S_   512
#define CP   256        // x-tile row = 512 B (swizzled)
#define NT   64         // spatial tile per block
#define SLAB_BYTES 16384            // 256 rows * 64B, swizzle-grouped
#define SLAB_ELEMS 8192             // halfwords
#define XT_BYTES (NT * CP * 2)      // 32768
#define LAYER_SLAB_ELEMS (B_ * 8 * SLAB_ELEMS)
#define NSTEPS 24                   // 3 layers * 8 K-steps

typedef __attribute__((ext_vector_type(8))) short bf16x8;
typedef __attribute__((ext_vector_type(4))) float f32x4;

__device__ __forceinline__ uint16_t f2bf(float f) {
  union { float f; uint32_t u; } v; v.f = f;
  return (uint16_t)((v.u + 0x7FFFu + ((v.u >> 16) & 1u)) >> 16);
}
__device__ __forceinline__ void gl_lds16(const void* g, void* l) {
  __builtin_amdgcn_global_load_lds(
      (const __attribute__((address_space(1))) void*)g,
      (__attribute__((address_space(3))) void*)l, 16, 0, 0);
}
__device__ __forceinline__ uint16_t actbf(float v) {
  v = (v >= 0.f) ? v : 0.2f * v;
  return f2bf(v * 1.4142135623730951f);
}
__device__ __forceinline__ float actf(float v) {
  v = (v >= 0.f) ? v : 0.2f * v;
  return v * 1.4142135623730951f;
}

// ---------------------------------------------------------------------------
// Weight kernel, all 3 layers in one launch: blockIdx.x = sample,
// blockIdx.y = layer. fp32 inputs.
// style = (z @ mw^T)/sqrt(S) + mb ; wb = w*style/sqrt(Cin) ; demod ; -> bf16
// Slab layout per (l,b,ks): [rowgroup 32][q 4][row8 8][8 halfwords];
// chunk (r,q) holds W[r][ks*32 + q*8 .. +8]. 16384 B per slab.
// ---------------------------------------------------------------------------
__global__ __launch_bounds__(256) void wkern(
    const float* __restrict__ z,
    const float* __restrict__ w0, const float* __restrict__ mw0,
    const float* __restrict__ mb0,
    const float* __restrict__ w1, const float* __restrict__ mw1,
    const float* __restrict__ mb1,
    const float* __restrict__ w2, const float* __restrict__ mw2,
    const float* __restrict__ mb2,
    uint16_t* __restrict__ slabs) {
  __shared__ float zsh[S_];
  __shared__ float stylesh[C_];
  const int b = blockIdx.x;
  const int l = blockIdx.y;
  const int t = threadIdx.x;
  const float* w  = (l == 0) ? w0  : (l == 1) ? w1  : w2;
  const float* mw = (l == 0) ? mw0 : (l == 1) ? mw1 : mw2;
  const float* mb = (l == 0) ? mb0 : (l == 1) ? mb1 : mb2;
  uint16_t* slab_l = slabs + (size_t)l * LAYER_SLAB_ELEMS;

  zsh[t]       = z[b * S_ + t];
  zsh[t + 256] = z[b * S_ + t + 256];
  __syncthreads();

  {  // style for input channel t
    const float* row = mw + (size_t)t * S_;
    float dot = 0.f;
    for (int j = 0; j < S_; j += 4) {
      float4 a = *(const float4*)(row + j);
      dot = fmaf(a.x, zsh[j + 0], dot);
      dot = fmaf(a.y, zsh[j + 1], dot);
      dot = fmaf(a.z, zsh[j + 2], dot);
      dot = fmaf(a.w, zsh[j + 3], dot);
    }
    stylesh[t] = dot * 0.04419417382415922f /*1/sqrt(512)*/ + mb[t];
  }
  __syncthreads();

  // output row t: modulate, demodulate, pack bf16 into K-blocked slabs
  const float* wrow = w + (size_t)t * C_;
  float ssum = 0.f;
  for (int i = 0; i < C_; i += 4) {
    float4 a = *(const float4*)(wrow + i);
    float t0 = 0.0625f * a.x * stylesh[i + 0];
    float t1 = 0.0625f * a.y * stylesh[i + 1];
    float t2 = 0.0625f * a.z * stylesh[i + 2];
    float t3 = 0.0625f * a.w * stylesh[i + 3];
    ssum = fmaf(t0, t0, fmaf(t1, t1, fmaf(t2, t2, fmaf(t3, t3, ssum))));
  }
  const float demod = rsqrtf(ssum + 1e-8f);
  for (int i = 0; i < C_; i += 8) {
    uint16_t hv[8];
#pragma unroll
    for (int k = 0; k < 8; ++k)
      hv[k] = f2bf(0.0625f * wrow[i + k] * stylesh[i + k] * demod);
    uint4 o;
    o.x = (uint32_t)hv[0] | ((uint32_t)hv[1] << 16);
    o.y = (uint32_t)hv[2] | ((uint32_t)hv[3] << 16);
    o.z = (uint32_t)hv[4] | ((uint32_t)hv[5] << 16);
    o.w = (uint32_t)hv[6] | ((uint32_t)hv[7] << 16);
    const int ks = i >> 5, q = (i & 31) >> 3;
    // halfword offset: rowgroup*256 + q*64 + (row&7)*8
    *(uint4*)(slab_l + (size_t)(b * 8 + ks) * SLAB_ELEMS +
              ((t >> 3) * 256 + q * 64 + (t & 7) * 8)) = o;
  }
}

// ---------------------------------------------------------------------------
// Fused 3-layer GEMM. One block = (sample b, 64-column n-tile).
// LDS: [0, XT)            x-tile, bf16 (n, 256) XOR-swizzled -- per layer
//      [XT, XT+16384)     W slab buf0
//      [XT+16384, +32768) W slab buf1
// x-tile addressing: byte = n*512 + (colbyte ^ ((n&7)<<4)).
// W-slab read: byte = (row>>3)*512 + q*128 + (row&7)*16  (slot = row&7).
// ---------------------------------------------------------------------------
__global__ __launch_bounds__(256, 2) void fused(
    const float* __restrict__ xg, const uint16_t* __restrict__ slabs,
    const float* __restrict__ b0, const float* __restrict__ b1,
    const float* __restrict__ b2, float* __restrict__ out) {
  __shared__ __align__(16) unsigned char lds[XT_BYTES + 2 * SLAB_BYTES];
  const int bx = blockIdx.x;
  const int b = bx >> 8, tl = bx & 255;
  const int n0 = tl * NT;
  const int t = threadIdx.x;
  const int wv = t >> 6, lane = t & 63;
  const int ln = lane & 15, q = lane >> 4;

  const char* slabc = (const char*)slabs;

  // --- prologue: stage step 0 (layer 0, ks 0) into buf0 -------------------
  {
    const char* wsrc = slabc + (size_t)(b * 8) * SLAB_BYTES;
    for (int i = wv; i < 16; i += 4)
      gl_lds16(wsrc + i * 1024 + lane * 16, lds + XT_BYTES + i * 1024);
  }
  // --- x tile: (c, n) fp32 -> (n, 256) bf16, swizzled ---------------------
  const float* xb = xg + (size_t)b * C_ * N_ + n0;
  const int nsw = (lane & 7) << 4;  // XOR swizzle for row n=lane
  for (int ks = 0; ks < 8; ++ks) {
    uint16_t hv[8];
#pragma unroll
    for (int i = 0; i < 8; ++i)
      hv[i] = f2bf(xb[(size_t)(ks * 32 + wv * 8 + i) * N_ + lane]);
    uint4 o;
    o.x = (uint32_t)hv[0] | ((uint32_t)hv[1] << 16);
    o.y = (uint32_t)hv[2] | ((uint32_t)hv[3] << 16);
    o.z = (uint32_t)hv[4] | ((uint32_t)hv[5] << 16);
    o.w = (uint32_t)hv[6] | ((uint32_t)hv[7] << 16);
    *(uint4*)(lds + lane * 512 + ((ks * 64 + wv * 16) ^ nsw)) = o;
  }
  __syncthreads();  // full drain once: buf0 + x-tile ready

  f32x4 acc[4][4];
#pragma unroll
  for (int mi = 0; mi < 4; ++mi)
#pragma unroll
    for (int ni = 0; ni < 4; ++ni) acc[mi][ni] = (f32x4){0.f, 0.f, 0.f, 0.f};

  for (int s = 0; s < NSTEPS; ++s) {
    const int l = s >> 3, ks = s & 7;
    const char* rbuf = (const char*)lds + XT_BYTES + (s & 1) * SLAB_BYTES;

    // stage next step's W slab into the other buffer (in flight across MFMA)
    if (s + 1 < NSTEPS) {
      const int sn = s + 1;
      const char* wsrc = slabc +
          ((size_t)(sn >> 3) * (B_ * 8) + b * 8 + (sn & 7)) * SLAB_BYTES;
      char* wdst = (char*)lds + XT_BYTES + ((s + 1) & 1) * SLAB_BYTES;
      for (int i = wv; i < 16; i += 4)
        gl_lds16(wsrc + i * 1024 + lane * 16, wdst + i * 1024);
    }

    // fragments + MFMA for current step
    bf16x8 af[4], bfr[4];
#pragma unroll
    for (int mi = 0; mi < 4; ++mi) {
      const int row = wv * 64 + mi * 16 + ln;
      af[mi] = *(const bf16x8*)(rbuf + (row >> 3) * 512 + q * 128 +
                                (row & 7) * 16);
    }
#pragma unroll
    for (int ni = 0; ni < 4; ++ni) {
      const int n = ni * 16 + ln;
      bfr[ni] = *(const bf16x8*)(lds + n * 512 +
                                 ((ks * 64 + q * 16) ^ ((n & 7) << 4)));
    }
#pragma unroll
    for (int mi = 0; mi < 4; ++mi)
#pragma unroll
      for (int ni = 0; ni < 4; ++ni)
        acc[mi][ni] = __builtin_amdgcn_mfma_f32_16x16x32_bf16(
            af[mi], bfr[ni], acc[mi][ni], 0, 0, 0);

    if (s + 1 < NSTEPS) {
      // next slab fully landed; all waves' reads of rbuf/xt done past here
      asm volatile("s_waitcnt vmcnt(0)" ::: "memory");
      __builtin_amdgcn_s_barrier();
      __builtin_amdgcn_sched_barrier(0);
    }

    if (ks == 7) {
      if (l < 2) {
        // layer epilogue: bias + act -> bf16, rewrite x-tile for next layer
        const float* bias = (l == 0) ? b0 : b1;
#pragma unroll
        for (int mi = 0; mi < 4; ++mi) {
          const int cb = wv * 64 + mi * 16 + q * 4;
          float4 b4 = *(const float4*)(bias + cb);
#pragma unroll
          for (int ni = 0; ni < 4; ++ni) {
            const int n = ni * 16 + ln;
            uint16_t h0 = actbf(acc[mi][ni][0] + b4.x);
            uint16_t h1 = actbf(acc[mi][ni][1] + b4.y);
            uint16_t h2 = actbf(acc[mi][ni][2] + b4.z);
            uint16_t h3 = actbf(acc[mi][ni][3] + b4.w);
            uint2 pk;
            pk.x = (uint32_t)h0 | ((uint32_t)h1 << 16);
            pk.y = (uint32_t)h2 | ((uint32_t)h3 << 16);
            *(uint2*)(lds + n * 512 + ((cb * 2) ^ ((n & 7) << 4))) = pk;
            acc[mi][ni] = (f32x4){0.f, 0.f, 0.f, 0.f};
          }
        }
        asm volatile("s_waitcnt lgkmcnt(0)" ::: "memory");
        __builtin_amdgcn_s_barrier();
        __builtin_amdgcn_sched_barrier(0);
      } else {
        // final layer: fp32 native (b, co, n) store straight from registers
        float* obase = out + (size_t)b * C_ * N_ + n0;
#pragma unroll
        for (int mi = 0; mi < 4; ++mi) {
          const int cb = wv * 64 + mi * 16 + q * 4;
          float4 b4 = *(const float4*)(b2 + cb);
          float bb[4] = {b4.x, b4.y, b4.z, b4.w};
#pragma unroll
          for (int ni = 0; ni < 4; ++ni) {
            const int n = ni * 16 + ln;
#pragma unroll
            for (int r = 0; r < 4; ++r)
              obase[(size_t)(cb + r) * N_ + n] = actf(acc[mi][ni][r] + bb[r]);
          }
        }
      }
    }
  }
}

// ---------------------------------------------------------------------------
extern "C" void kernel_launch(void* const* d_in, const int* in_sizes, int n_in,
                              void* d_out, int out_size, void* d_ws,
                              size_t ws_size, hipStream_t stream) {
  (void)in_sizes; (void)n_in; (void)out_size; (void)ws_size;
  const float* x = (const float*)d_in[0];
  const float* z = (const float*)d_in[1];
  const float* w0  = (const float*)d_in[2];
  const float* mw0 = (const float*)d_in[3];
  const float* mb0 = (const float*)d_in[4];
  const float* bb0 = (const float*)d_in[5];
  const float* w1  = (const float*)d_in[6];
  const float* mw1 = (const float*)d_in[7];
  const float* mb1 = (const float*)d_in[8];
  const float* bb1 = (const float*)d_in[9];
  const float* w2  = (const float*)d_in[10];
  const float* mw2 = (const float*)d_in[11];
  const float* mb2 = (const float*)d_in[12];
  const float* bb2 = (const float*)d_in[13];

  uint16_t* wslabs = (uint16_t*)d_ws;  // 6 MB (3 layers)

  wkern<<<dim3(B_, 3), 256, 0, stream>>>(z, w0, mw0, mb0, w1, mw1, mb1,
                                         w2, mw2, mb2, wslabs);
  fused<<<B_ * 256, 256, 0, stream>>>(x, wslabs, bb0, bb1, bb2,
                                      (float*)d_out);
}

// Round 3
// 608.536 us; speedup vs baseline: 1.3512x; 1.0314x over previous
//
#include <hip/hip_runtime.h>
#include <stdint.h>

// ---------------------------------------------------------------------------
// StyledMLP fp32 I/O: 3x (modulated 1x1 conv + bias + leaky_relu*sqrt2).
// Internal compute: bf16 MFMA (16x16x32), fp32 accumulate.
// FULLY FUSED: 1x1 convs are column-local; one block owns a 64-column n-tile
// and runs all 3 layers in LDS. h0/h1 never touch HBM.
// R2: T2 bank-conflict swizzles (x-tile XOR, W slab [rg32][q4][r8][16B]).
// R3: T4 counted-vmcnt pipeline, prefetch depth 2, 3 W-slab buffers.
//     End-of-step waits vmcnt(4): the slab for step s+1 (issued at s-1) is
//     already landed; step s+2's 4 loads stay in flight across the barrier.
//     LDS = 32K x-tile + 3x16K W = 81920 B -> exactly 2 blocks/CU.
// ---------------------------------------------------------------------------

#define B_   16
#define C_   256        // Cin = Chid = Cout
#define N_   16384
#define S_   512
#define NT   64         // spatial tile per block
#define SLAB_BYTES 16384            // 256 rows * 64B, swizzle-grouped
#define SLAB_ELEMS 8192             // halfwords
#define XT_BYTES (NT * 256 * 2)     // 32768
#define LAYER_SLAB_ELEMS (B_ * 8 * SLAB_ELEMS)
#define NSTEPS 24                   // 3 layers * 8 K-steps

typedef __attribute__((ext_vector_type(8))) short bf16x8;
typedef __attribute__((ext_vector_type(4))) float f32x4;

__device__ __forceinline__ uint16_t f2bf(float f) {
  union { float f; uint32_t u; } v; v.f = f;
  return (uint16_t)((v.u + 0x7FFFu + ((v.u >> 16) & 1u)) >> 16);
}
__device__ __forceinline__ void gl_lds16(const void* g, void* l) {
  __builtin_amdgcn_global_load_lds(
      (const __attribute__((address_space(1))) void*)g,
      (__attribute__((address_space(3))) void*)l, 16, 0, 0);
}
__device__ __forceinline__ uint16_t actbf(float v) {
  v = (v >= 0.f) ? v : 0.2f * v;
  return f2bf(v * 1.4142135623730951f);
}
__device__ __forceinline__ float actf(float v) {
  v = (v >= 0.f) ? v : 0.2f * v;
  return v * 1.4142135623730951f;
}

// ---------------------------------------------------------------------------
// Weight kernel, all 3 layers in one launch: blockIdx.x = sample,
// blockIdx.y = layer. fp32 inputs.
// style = (z @ mw^T)/sqrt(S) + mb ; wb = w*style/sqrt(Cin) ; demod ; -> bf16
// Slab layout per (l,b,ks): [rowgroup 32][q 4][row8 8][8 halfwords];
// chunk (r,q) holds W[r][ks*32 + q*8 .. +8]. 16384 B per slab.
// ---------------------------------------------------------------------------
__global__ __launch_bounds__(256) void wkern(
    const float* __restrict__ z,
    const float* __restrict__ w0, const float* __restrict__ mw0,
    const float* __restrict__ mb0,
    const float* __restrict__ w1, const float* __restrict__ mw1,
    const float* __restrict__ mb1,
    const float* __restrict__ w2, const float* __restrict__ mw2,
    const float* __restrict__ mb2,
    uint16_t* __restrict__ slabs) {
  __shared__ float zsh[S_];
  __shared__ float stylesh[C_];
  const int b = blockIdx.x;
  const int l = blockIdx.y;
  const int t = threadIdx.x;
  const float* w  = (l == 0) ? w0  : (l == 1) ? w1  : w2;
  const float* mw = (l == 0) ? mw0 : (l == 1) ? mw1 : mw2;
  const float* mb = (l == 0) ? mb0 : (l == 1) ? mb1 : mb2;
  uint16_t* slab_l = slabs + (size_t)l * LAYER_SLAB_ELEMS;

  zsh[t]       = z[b * S_ + t];
  zsh[t + 256] = z[b * S_ + t + 256];
  __syncthreads();

  {  // style for input channel t
    const float* row = mw + (size_t)t * S_;
    float dot = 0.f;
    for (int j = 0; j < S_; j += 4) {
      float4 a = *(const float4*)(row + j);
      dot = fmaf(a.x, zsh[j + 0], dot);
      dot = fmaf(a.y, zsh[j + 1], dot);
      dot = fmaf(a.z, zsh[j + 2], dot);
      dot = fmaf(a.w, zsh[j + 3], dot);
    }
    stylesh[t] = dot * 0.04419417382415922f /*1/sqrt(512)*/ + mb[t];
  }
  __syncthreads();

  // output row t: modulate, demodulate, pack bf16 into K-blocked slabs
  const float* wrow = w + (size_t)t * C_;
  float ssum = 0.f;
  for (int i = 0; i < C_; i += 4) {
    float4 a = *(const float4*)(wrow + i);
    float t0 = 0.0625f * a.x * stylesh[i + 0];
    float t1 = 0.0625f * a.y * stylesh[i + 1];
    float t2 = 0.0625f * a.z * stylesh[i + 2];
    float t3 = 0.0625f * a.w * stylesh[i + 3];
    ssum = fmaf(t0, t0, fmaf(t1, t1, fmaf(t2, t2, fmaf(t3, t3, ssum))));
  }
  const float demod = rsqrtf(ssum + 1e-8f);
  for (int i = 0; i < C_; i += 8) {
    uint16_t hv[8];
#pragma unroll
    for (int k = 0; k < 8; ++k)
      hv[k] = f2bf(0.0625f * wrow[i + k] * stylesh[i + k] * demod);
    uint4 o;
    o.x = (uint32_t)hv[0] | ((uint32_t)hv[1] << 16);
    o.y = (uint32_t)hv[2] | ((uint32_t)hv[3] << 16);
    o.z = (uint32_t)hv[4] | ((uint32_t)hv[5] << 16);
    o.w = (uint32_t)hv[6] | ((uint32_t)hv[7] << 16);
    const int ks = i >> 5, q = (i & 31) >> 3;
    // halfword offset: rowgroup*256 + q*64 + (row&7)*8
    *(uint4*)(slab_l + (size_t)(b * 8 + ks) * SLAB_ELEMS +
              ((t >> 3) * 256 + q * 64 + (t & 7) * 8)) = o;
  }
}

// ---------------------------------------------------------------------------
// Fused 3-layer GEMM. One block = (sample b, 64-column n-tile).
// LDS: [0, 32K)       x-tile, bf16 (n, 256) XOR-swizzled -- per layer
//      [32K, 80K)     W slab ring buffer (3 x 16K)
// x-tile addressing: byte = n*512 + (colbyte ^ ((n&7)<<4)).
// W-slab read: byte = (row>>3)*512 + q*128 + (row&7)*16  (slot = row&7).
// Pipeline: step s issues stage(s+2); end-of-step waits lgkmcnt(0) (this
// step's ds_reads done -> safe for next step's DMA into buf[s%3]) +
// vmcnt(4) (stage(s+1) landed; stage(s+2) in flight) + barrier.
// ---------------------------------------------------------------------------
__global__ __launch_bounds__(256, 2) void fused(
    const float* __restrict__ xg, const uint16_t* __restrict__ slabs,
    const float* __restrict__ b0, const float* __restrict__ b1,
    const float* __restrict__ b2, float* __restrict__ out) {
  __shared__ __align__(16) unsigned char lds[XT_BYTES + 3 * SLAB_BYTES];
  const int bx = blockIdx.x;
  const int b = bx >> 8, tl = bx & 255;
  const int n0 = tl * NT;
  const int t = threadIdx.x;
  const int wv = t >> 6, lane = t & 63;
  const int ln = lane & 15, q = lane >> 4;

  const char* slabc = (const char*)slabs;
  char* ldsW = (char*)lds + XT_BYTES;

  // --- prologue: stage steps 0 and 1 into buf0/buf1 -----------------------
  {
    const char* s0 = slabc + (size_t)(b * 8 + 0) * SLAB_BYTES;
    const char* s1 = slabc + (size_t)(b * 8 + 1) * SLAB_BYTES;
    for (int i = wv; i < 16; i += 4)
      gl_lds16(s0 + i * 1024 + lane * 16, ldsW + i * 1024);
    for (int i = wv; i < 16; i += 4)
      gl_lds16(s1 + i * 1024 + lane * 16, ldsW + SLAB_BYTES + i * 1024);
  }
  // --- x tile: (c, n) fp32 -> (n, 256) bf16, swizzled ---------------------
  const float* xb = xg + (size_t)b * C_ * N_ + n0;
  const int nsw = (lane & 7) << 4;  // XOR swizzle for row n=lane
  for (int ks = 0; ks < 8; ++ks) {
    uint16_t hv[8];
#pragma unroll
    for (int i = 0; i < 8; ++i)
      hv[i] = f2bf(xb[(size_t)(ks * 32 + wv * 8 + i) * N_ + lane]);
    uint4 o;
    o.x = (uint32_t)hv[0] | ((uint32_t)hv[1] << 16);
    o.y = (uint32_t)hv[2] | ((uint32_t)hv[3] << 16);
    o.z = (uint32_t)hv[4] | ((uint32_t)hv[5] << 16);
    o.w = (uint32_t)hv[6] | ((uint32_t)hv[7] << 16);
    *(uint4*)(lds + lane * 512 + ((ks * 64 + wv * 16) ^ nsw)) = o;
  }
  asm volatile("s_waitcnt lgkmcnt(0) vmcnt(0)" ::: "memory");
  __builtin_amdgcn_s_barrier();
  __builtin_amdgcn_sched_barrier(0);

  f32x4 acc[4][4];
#pragma unroll
  for (int mi = 0; mi < 4; ++mi)
#pragma unroll
    for (int ni = 0; ni < 4; ++ni) acc[mi][ni] = (f32x4){0.f, 0.f, 0.f, 0.f};

  int bcur = 0;  // ring index of the slab for step s
  for (int s = 0; s < NSTEPS; ++s) {
    const int ks = s & 7;
    const char* rbuf = ldsW + bcur * SLAB_BYTES;

    // stage step s+2's W slab (in flight across this step's barrier)
    if (s + 2 < NSTEPS) {
      const int sn = s + 2;
      int bst = bcur + 2; if (bst >= 3) bst -= 3;
      const char* wsrc = slabc +
          ((size_t)(sn >> 3) * (B_ * 8) + b * 8 + (sn & 7)) * SLAB_BYTES;
      char* wdst = ldsW + bst * SLAB_BYTES;
      for (int i = wv; i < 16; i += 4)
        gl_lds16(wsrc + i * 1024 + lane * 16, wdst + i * 1024);
    }

    // fragments + MFMA for current step
    bf16x8 af[4], bfr[4];
#pragma unroll
    for (int mi = 0; mi < 4; ++mi) {
      const int row = wv * 64 + mi * 16 + ln;
      af[mi] = *(const bf16x8*)(rbuf + (row >> 3) * 512 + q * 128 +
                                (row & 7) * 16);
    }
#pragma unroll
    for (int ni = 0; ni < 4; ++ni) {
      const int n = ni * 16 + ln;
      bfr[ni] = *(const bf16x8*)(lds + n * 512 +
                                 ((ks * 64 + q * 16) ^ ((n & 7) << 4)));
    }
#pragma unroll
    for (int mi = 0; mi < 4; ++mi)
#pragma unroll
      for (int ni = 0; ni < 4; ++ni)
        acc[mi][ni] = __builtin_amdgcn_mfma_f32_16x16x32_bf16(
            af[mi], bfr[ni], acc[mi][ni], 0, 0, 0);

    if (s == NSTEPS - 1) break;  // last step: no more LDS use, go store

    // end-of-step sync: my ds_reads complete (DMA will overwrite buf[bcur]
    // next step); stage(s+1) landed for everyone; stage(s+2) stays in flight
    asm volatile("s_waitcnt lgkmcnt(0)" ::: "memory");
    if (s + 2 < NSTEPS)
      asm volatile("s_waitcnt vmcnt(4)" ::: "memory");
    else
      asm volatile("s_waitcnt vmcnt(0)" ::: "memory");
    __builtin_amdgcn_s_barrier();
    __builtin_amdgcn_sched_barrier(0);

    if (ks == 7) {
      // layer epilogue: bias + act -> bf16, rewrite x-tile for next layer
      const float* bias = (s >> 3) ? b1 : b0;
#pragma unroll
      for (int mi = 0; mi < 4; ++mi) {
        const int cb = wv * 64 + mi * 16 + q * 4;
        float4 b4 = *(const float4*)(bias + cb);
#pragma unroll
        for (int ni = 0; ni < 4; ++ni) {
          const int n = ni * 16 + ln;
          uint16_t h0 = actbf(acc[mi][ni][0] + b4.x);
          uint16_t h1 = actbf(acc[mi][ni][1] + b4.y);
          uint16_t h2 = actbf(acc[mi][ni][2] + b4.z);
          uint16_t h3 = actbf(acc[mi][ni][3] + b4.w);
          uint2 pk;
          pk.x = (uint32_t)h0 | ((uint32_t)h1 << 16);
          pk.y = (uint32_t)h2 | ((uint32_t)h3 << 16);
          *(uint2*)(lds + n * 512 + ((cb * 2) ^ ((n & 7) << 4))) = pk;
          acc[mi][ni] = (f32x4){0.f, 0.f, 0.f, 0.f};
        }
      }
      asm volatile("s_waitcnt lgkmcnt(0)" ::: "memory");
      __builtin_amdgcn_s_barrier();
      __builtin_amdgcn_sched_barrier(0);
    }

    bcur = (bcur == 2) ? 0 : bcur + 1;
  }

  // final layer: fp32 native (b, co, n) store straight from registers
  {
    float* obase = out + (size_t)b * C_ * N_ + n0;
#pragma unroll
    for (int mi = 0; mi < 4; ++mi) {
      const int cb = wv * 64 + mi * 16 + q * 4;
      float4 b4 = *(const float4*)(b2 + cb);
      float bb[4] = {b4.x, b4.y, b4.z, b4.w};
#pragma unroll
      for (int ni = 0; ni < 4; ++ni) {
        const int n = ni * 16 + ln;
#pragma unroll
        for (int r = 0; r < 4; ++r)
          obase[(size_t)(cb + r) * N_ + n] = actf(acc[mi][ni][r] + bb[r]);
      }
    }
  }
}

// ---------------------------------------------------------------------------
extern "C" void kernel_launch(void* const* d_in, const int* in_sizes, int n_in,
                              void* d_out, int out_size, void* d_ws,
                              size_t ws_size, hipStream_t stream) {
  (void)in_sizes; (void)n_in; (void)out_size; (void)ws_size;
  const float* x = (const float*)d_in[0];
  const float* z = (const float*)d_in[1];
  const float* w0  = (const float*)d_in[2];
  const float* mw0 = (const float*)d_in[3];
  const float* mb0 = (const float*)d_in[4];
  const float* bb0 = (const float*)d_in[5];
  const float* w1  = (const float*)d_in[6];
  const float* mw1 = (const float*)d_in[7];
  const float* mb1 = (const float*)d_in[8];
  const float* bb1 = (const float*)d_in[9];
  const float* w2  = (const float*)d_in[10];
  const float* mw2 = (const float*)d_in[11];
  const float* mb2 = (const float*)d_in[12];
  const float* bb2 = (const float*)d_in[13];

  uint16_t* wslabs = (uint16_t*)d_ws;  // 6 MB (3 layers)

  wkern<<<dim3(B_, 3), 256, 0, stream>>>(z, w0, mw0, mb0, w1, mw1, mb1,
                                         w2, mw2, mb2, wslabs);
  fused<<<B_ * 256, 256, 0, stream>>>(x, wslabs, bb0, bb1, bb2,
                                      (float*)d_out);
}